// Round 1
// baseline (86.936 us; speedup 1.0000x reference)
//
#include <hip/hip_runtime.h>

// AdderNet 2D: out[n,f,h,w] = -sum_{c,kh,kw} |W[f,c,kh,kw] - xpad[n,c,h+kh,w+kw]|
// x: (16,64,14,14) fp32, W: (64,64,3,3) fp32, out: (16,64,14,14) fp32
// K=3, stride=1, pad=1 -> H_out=W_out=14.

#define N_ 16
#define C_ 64
#define F_ 64
#define H_ 14
#define W_ 14
#define P_ 196        // 14*14 output pixels
#define D_ 576        // 64*9
#define CHUNK 8       // channels staged per LDS round
#define LDS_STRIDE 17 // 16 cols + 1 pad to break bank aliasing

__global__ __launch_bounds__(256) void adder2d_kernel(
    const float* __restrict__ x, const float* __restrict__ w,
    float* __restrict__ out)
{
    // 8 channels x (16 rows x 17 stride) = 8704 B LDS
    __shared__ float xt[CHUNK][16 * LDS_STRIDE];

    const int f   = blockIdx.x;   // 0..63
    const int n   = blockIdx.y;   // 0..15
    const int tid = threadIdx.x;  // 0..255

    // compute mapping: one output pixel per thread (196 active)
    const int p    = tid;
    const int h    = p / 14;
    const int wcol = p % 14;

    // staging mapping: padded 16x16 tile, one element per thread
    const int ph = tid >> 4;  // padded row 0..15
    const int pw = tid & 15;  // padded col 0..15
    const bool interior = (ph >= 1) && (ph <= 14) && (pw >= 1) && (pw <= 14);
    // x[((n*64 + c)*14 + (ph-1))*14 + (pw-1)]
    const int xbase = n * C_ * (H_ * W_) + (ph - 1) * W_ + (pw - 1);

    const float* wf = w + f * D_;  // block-uniform -> scalar loads

    // 3 accumulators to break the dependent-add chain
    float acc0 = 0.0f, acc1 = 0.0f, acc2 = 0.0f;

    for (int chunk = 0; chunk < C_ / CHUNK; ++chunk) {
        // ---- stage CHUNK padded channel tiles into LDS ----
        #pragma unroll
        for (int i = 0; i < CHUNK; ++i) {
            const int c = chunk * CHUNK + i;
            float v = 0.0f;
            if (interior) v = x[xbase + c * (H_ * W_)];
            xt[i][ph * LDS_STRIDE + pw] = v;
        }
        __syncthreads();

        // ---- accumulate 9 abs-diffs per channel ----
        if (p < P_) {
            #pragma unroll
            for (int i = 0; i < CHUNK; ++i) {
                const int c = chunk * CHUNK + i;
                const float* wr = wf + c * 9;            // uniform -> SGPR
                const float* r0 = &xt[i][(h + 0) * LDS_STRIDE + wcol];
                const float* r1 = &xt[i][(h + 1) * LDS_STRIDE + wcol];
                const float* r2 = &xt[i][(h + 2) * LDS_STRIDE + wcol];
                acc0 += fabsf(wr[0] - r0[0]);
                acc1 += fabsf(wr[1] - r0[1]);
                acc2 += fabsf(wr[2] - r0[2]);
                acc0 += fabsf(wr[3] - r1[0]);
                acc1 += fabsf(wr[4] - r1[1]);
                acc2 += fabsf(wr[5] - r1[2]);
                acc0 += fabsf(wr[6] - r2[0]);
                acc1 += fabsf(wr[7] - r2[1]);
                acc2 += fabsf(wr[8] - r2[2]);
            }
        }
        __syncthreads();
    }

    if (p < P_) {
        out[(n * F_ + f) * P_ + p] = -(acc0 + acc1 + acc2);
    }
}

extern "C" void kernel_launch(void* const* d_in, const int* in_sizes, int n_in,
                              void* d_out, int out_size, void* d_ws, size_t ws_size,
                              hipStream_t stream) {
    const float* x = (const float*)d_in[0];
    const float* w = (const float*)d_in[1];
    float* out = (float*)d_out;
    dim3 grid(F_, N_);
    adder2d_kernel<<<grid, 256, 0, stream>>>(x, w, out);
}

// Round 2
// 84.609 us; speedup vs baseline: 1.0275x; 1.0275x over previous
//
#include <hip/hip_runtime.h>

// AdderNet 2D: out[n,f,h,w] = -sum_{c,kh,kw} |W[f,c,kh,kw] - xpad[n,c,h+kh,w+kw]|
// x: (16,64,14,14) fp32, W: (64,64,3,3) fp32, out: (16,64,14,14) fp32
//
// R2 structure: grid = (fg=16, n=16) = 256 blocks x 256 threads.
// Block stages the FULL padded image (64ch x 16x17 = 68KB LDS) once,
// then thread = 1 output pixel x 4 filters. Each LDS read amortized
// over 4 f-accumulators; W reads are block-uniform -> scalar loads.

#define N_ 16
#define C_ 64
#define F_ 64
#define H_ 14
#define W_ 14
#define P_ 196
#define RS 17             // padded row stride (16 cols + 1 bank-break)
#define CH_WORDS (16*RS)  // 272 words per channel
#define NT 4              // filters per block

__global__ __launch_bounds__(256) void adder2d_kernel(
    const float* __restrict__ x, const float* __restrict__ w,
    float* __restrict__ out)
{
    __shared__ __align__(16) float xt[C_ * CH_WORDS];  // 69632 B

    const int tid = threadIdx.x;
    const int fg  = blockIdx.x;   // 0..15  -> filters fg*4 .. fg*4+3
    const int n   = blockIdx.y;   // 0..15

    // ---- zero the whole LDS tile (covers padding halo) ----
    float4* xt4 = (float4*)xt;
    #pragma unroll
    for (int i = 0; i < 17; ++i)   // 17*256*4 = 17408 words
        xt4[i * 256 + tid] = make_float4(0.f, 0.f, 0.f, 0.f);
    __syncthreads();

    // ---- stage interior: 64 channels x 196 floats = 3136 float4 ----
    const float4* xv4 = (const float4*)(x + n * (C_ * P_));
    for (int idx = tid; idx < 3136; idx += 256) {
        unsigned c = (unsigned)idx / 49u;
        unsigned q = (unsigned)idx - c * 49u;
        float4 v = xv4[c * 49u + q];
        unsigned e = q * 4u;
        float vv[4] = {v.x, v.y, v.z, v.w};
        #pragma unroll
        for (int j = 0; j < 4; ++j) {
            unsigned ee  = e + j;
            unsigned r   = ee / 14u;
            unsigned col = ee - r * 14u;
            xt[c * CH_WORDS + (r + 1) * RS + (col + 1)] = vv[j];
        }
    }
    __syncthreads();

    // ---- compute: 1 pixel x 4 filters per thread ----
    if (tid < P_) {
        const unsigned h  = (unsigned)tid / 14u;
        const unsigned wv = (unsigned)tid - h * 14u;
        const int fbase = fg * NT;
        const float* wp = w + fbase * (C_ * 9);  // block-uniform

        float acc0 = 0.f, acc1 = 0.f, acc2 = 0.f, acc3 = 0.f;
        const float* xrow = xt + h * RS + wv;

        #pragma unroll 2
        for (int c = 0; c < C_; ++c) {
            const float* xc = xrow + c * CH_WORDS;
            // 9 x values for this (pixel, channel)
            float x0 = xc[0],      x1 = xc[1],        x2 = xc[2];
            float x3 = xc[RS],     x4 = xc[RS + 1],   x5 = xc[RS + 2];
            float x6 = xc[2*RS],   x7 = xc[2*RS + 1], x8 = xc[2*RS + 2];

            const float* w0 = wp + (0 * C_ + c) * 9;  // uniform -> SGPR
            const float* w1 = wp + (1 * C_ + c) * 9;
            const float* w2 = wp + (2 * C_ + c) * 9;
            const float* w3 = wp + (3 * C_ + c) * 9;

            acc0 += fabsf(w0[0]-x0) + fabsf(w0[1]-x1) + fabsf(w0[2]-x2)
                  + fabsf(w0[3]-x3) + fabsf(w0[4]-x4) + fabsf(w0[5]-x5)
                  + fabsf(w0[6]-x6) + fabsf(w0[7]-x7) + fabsf(w0[8]-x8);
            acc1 += fabsf(w1[0]-x0) + fabsf(w1[1]-x1) + fabsf(w1[2]-x2)
                  + fabsf(w1[3]-x3) + fabsf(w1[4]-x4) + fabsf(w1[5]-x5)
                  + fabsf(w1[6]-x6) + fabsf(w1[7]-x7) + fabsf(w1[8]-x8);
            acc2 += fabsf(w2[0]-x0) + fabsf(w2[1]-x1) + fabsf(w2[2]-x2)
                  + fabsf(w2[3]-x3) + fabsf(w2[4]-x4) + fabsf(w2[5]-x5)
                  + fabsf(w2[6]-x6) + fabsf(w2[7]-x7) + fabsf(w2[8]-x8);
            acc3 += fabsf(w3[0]-x0) + fabsf(w3[1]-x1) + fabsf(w3[2]-x2)
                  + fabsf(w3[3]-x3) + fabsf(w3[4]-x4) + fabsf(w3[5]-x5)
                  + fabsf(w3[6]-x6) + fabsf(w3[7]-x7) + fabsf(w3[8]-x8);
        }

        float* op = out + (n * F_ + fbase) * P_ + tid;
        op[0 * P_] = -acc0;
        op[1 * P_] = -acc1;
        op[2 * P_] = -acc2;
        op[3 * P_] = -acc3;
    }
}

extern "C" void kernel_launch(void* const* d_in, const int* in_sizes, int n_in,
                              void* d_out, int out_size, void* d_ws, size_t ws_size,
                              hipStream_t stream) {
    const float* x = (const float*)d_in[0];
    const float* w = (const float*)d_in[1];
    float* out = (float*)d_out;
    dim3 grid(F_ / NT, N_);
    adder2d_kernel<<<grid, 256, 0, stream>>>(x, w, out);
}